// Round 11
// baseline (2760.850 us; speedup 1.0000x reference)
//
#include <hip/hip_runtime.h>
#include <hip/hip_bf16.h>
#include <math.h>

#define BB 64
#define PP 196
#define CC 2048
#define DD 512
#define AA 512
#define EE 512
#define VV 30000
#define VPAD 30016
#define LL 32
#define TT 31
#define XH 2560      // [ctx*gate (2048) | h (512)]
#define HEADBLK 469  // VPAD/64

typedef short bf16x8 __attribute__((ext_vector_type(8)));
typedef float f32x4 __attribute__((ext_vector_type(4)));

__device__ inline unsigned short f2bf(float x) {
    __hip_bfloat16 h = __float2bfloat16(x);
    return __builtin_bit_cast(unsigned short, h);
}
__device__ inline float bf2f(unsigned short u) {
    unsigned int x = ((unsigned int)u) << 16;
    return __builtin_bit_cast(float, x);
}

// MFMA core over first NA m-tiles — branch-free, fully unrolled per instantiation.
template<int NA, int K, int LDA>
__device__ inline void mmN(const unsigned short* __restrict__ a0,
                           const unsigned short* __restrict__ b0,
                           f32x4 acc[4]) {
#pragma unroll
    for (int kc = 0; kc < K / 32; ++kc) {
        bf16x8 bfr = *reinterpret_cast<const bf16x8*>(b0 + kc * 32);
#pragma unroll
        for (int mt = 0; mt < NA; ++mt) {
            bf16x8 afr = *reinterpret_cast<const bf16x8*>(a0 + (size_t)mt * 16 * LDA + kc * 32);
            acc[mt] = __builtin_amdgcn_mfma_f32_16x16x32_bf16(afr, bfr, acc[mt], 0, 0, 0);
        }
    }
}

// uniform dispatch on active-tile count (prefix pattern)
template<int K, int LDA>
__device__ inline void mmD(int nAct, const unsigned short* __restrict__ a0,
                           const unsigned short* __restrict__ b0, f32x4 acc[4]) {
    switch (nAct) {
        case 4: mmN<4, K, LDA>(a0, b0, acc); break;
        case 3: mmN<3, K, LDA>(a0, b0, acc); break;
        case 2: mmN<2, K, LDA>(a0, b0, acc); break;
        case 1: mmN<1, K, LDA>(a0, b0, acc); break;
        default: break;
    }
}

// ---------- setup kernels ----------

__global__ void k_sort(const int* __restrict__ text, const int* __restrict__ lens,
                       int* __restrict__ idx, int* __restrict__ inv, int* __restrict__ tlen,
                       int* __restrict__ ts,
                       float* __restrict__ out_text, float* __restrict__ out_tlen,
                       float* __restrict__ out_idx) {
    int j = threadIdx.x;
    __shared__ int key[BB];
    __shared__ int sidx[BB];
    key[j] = lens[j];
    __syncthreads();
    int kj = key[j];
    int pos = 0;
    for (int q = 0; q < BB; ++q) {
        int kq = key[q];
        if (kq > kj || (kq == kj && q < j)) pos++;
    }
    sidx[pos] = j;
    __syncthreads();
    int src = sidx[j];
    idx[j] = src;
    inv[src] = j;
    int tl = key[src] - 1;
    tlen[j] = tl;
    out_idx[j] = (float)src;
    out_tlen[j] = (float)tl;
    for (int l = 0; l < LL; ++l) {
        int tok = text[src * LL + l];
        ts[j * LL + l] = tok;
        out_text[j * LL + l] = (float)tok;
    }
}

__global__ __launch_bounds__(256) void k_cvtenc(const float* __restrict__ enc, const int* __restrict__ idx,
                                                unsigned short* __restrict__ enc_bf) {
    int row = blockIdx.x;           // bs*196+p
    int bs = row / PP, p = row - bs * PP;
    int c0 = threadIdx.x * 8;
    const float* src = enc + ((size_t)idx[bs] * PP + p) * CC + c0;
    f32x4 lo = *reinterpret_cast<const f32x4*>(src);
    f32x4 hi = *reinterpret_cast<const f32x4*>(src + 4);
    unsigned short* dst = enc_bf + (size_t)row * CC + c0;
    bf16x8 v;
    v[0] = (short)f2bf(lo[0]); v[1] = (short)f2bf(lo[1]);
    v[2] = (short)f2bf(lo[2]); v[3] = (short)f2bf(lo[3]);
    v[4] = (short)f2bf(hi[0]); v[5] = (short)f2bf(hi[1]);
    v[6] = (short)f2bf(hi[2]); v[7] = (short)f2bf(hi[3]);
    *reinterpret_cast<bf16x8*>(dst) = v;
}

__global__ __launch_bounds__(256) void k_meanbf(const unsigned short* __restrict__ enc_bf,
                                                const int* __restrict__ inv,
                                                unsigned short* __restrict__ mean_bf) {
    int b = blockIdx.x;
    int lane = threadIdx.x & 31, pg = threadIdx.x >> 5;
    int c0 = blockIdx.y * 256 + lane * 8;
    const unsigned short* img = enc_bf + (size_t)inv[b] * PP * CC + c0;
    float s[8] = {0.f, 0.f, 0.f, 0.f, 0.f, 0.f, 0.f, 0.f};
    for (int p = pg; p < PP; p += 8) {
        bf16x8 v = *reinterpret_cast<const bf16x8*>(img + (size_t)p * CC);
#pragma unroll
        for (int j = 0; j < 8; ++j) s[j] += bf2f((unsigned short)v[j]);
    }
    __shared__ float red[8][256];
#pragma unroll
    for (int j = 0; j < 8; ++j) red[pg][lane * 8 + j] = s[j];
    __syncthreads();
    int c = threadIdx.x;
    float tt = 0.f;
#pragma unroll
    for (int g = 0; g < 8; ++g) tt += red[g][c];
    mean_bf[(size_t)b * CC + blockIdx.y * 256 + c] = f2bf(tt * (1.0f / PP));
}

__global__ __launch_bounds__(64) void k_init_mfma(const unsigned short* __restrict__ mean_bf,
                                                  const unsigned short* __restrict__ Wt_ih,
                                                  const unsigned short* __restrict__ Wt_ic,
                                                  const float* __restrict__ bh, const float* __restrict__ bc,
                                                  unsigned short* __restrict__ xh_bf, float* __restrict__ c_f32) {
    int isC = blockIdx.x >= 32;
    int n0 = (blockIdx.x & 31) * 16;
    int lane = threadIdx.x;
    const unsigned short* Wt = isC ? Wt_ic : Wt_ih;
    const unsigned short* a0 = mean_bf + (size_t)(lane & 15) * CC + ((lane >> 4) * 8);
    const unsigned short* b0 = Wt + (size_t)(n0 + (lane & 15)) * CC + ((lane >> 4) * 8);
    f32x4 acc[4];
#pragma unroll
    for (int mt = 0; mt < 4; ++mt) acc[mt] = (f32x4){0.f, 0.f, 0.f, 0.f};
    mmN<4, CC, CC>(a0, b0, acc);
    int n = n0 + (lane & 15);
    float bv = (isC ? bc : bh)[n];
#pragma unroll
    for (int mt = 0; mt < 4; ++mt)
#pragma unroll
        for (int r = 0; r < 4; ++r) {
            int m = mt * 16 + (lane >> 4) * 4 + r;
            float val = acc[mt][r] + bv;
            if (isC) c_f32[(size_t)m * DD + n] = val;
            else     xh_bf[(size_t)m * XH + CC + n] = f2bf(val);
        }
}

__global__ __launch_bounds__(256) void k_transcvt(const float* __restrict__ src, int K, int N,
                                                  unsigned short* __restrict__ dst, int dstStride, int Npad) {
    __shared__ float t[32][33];
    int n0 = blockIdx.x * 32, k0 = blockIdx.y * 32;
    int tx = threadIdx.x, ty = threadIdx.y;
#pragma unroll
    for (int r = 0; r < 4; ++r) {
        int k = k0 + ty + r * 8;
        int n = n0 + tx;
        t[ty + r * 8][tx] = (n < N) ? src[(size_t)k * N + n] : 0.f;
    }
    __syncthreads();
#pragma unroll
    for (int r = 0; r < 4; ++r) {
        int n = n0 + ty + r * 8;
        int k = k0 + tx;
        if (n < Npad) dst[(size_t)n * dstStride + k] = f2bf(t[tx][ty + r * 8]);
    }
}

__global__ __launch_bounds__(256) void k_emball(const float* __restrict__ embed, const int* __restrict__ ts,
                                                unsigned short* __restrict__ emb_all) {
    int row = blockIdx.x;           // t*64+b
    int t = row >> 6, b = row & 63;
    int tok = ts[b * LL + t];
    int e = threadIdx.x * 2;
    const float* src = embed + (size_t)tok * EE + e;
    unsigned short* dst = emb_all + (size_t)row * EE + e;
    dst[0] = f2bf(src[0]);
    dst[1] = f2bf(src[1]);
}

__global__ __launch_bounds__(256) void k_embw(const unsigned short* __restrict__ emb_all,
                                              const unsigned short* __restrict__ Wt_emb,
                                              const float* __restrict__ bih, const float* __restrict__ bhh,
                                              float* __restrict__ embW) {
    int tstep = blockIdx.x;
    int n0 = blockIdx.y * 64;
    int lane = threadIdx.x & 63, w = threadIdx.x >> 6;
    const unsigned short* a0 = emb_all + ((size_t)tstep * 64 + (lane & 15)) * EE + ((lane >> 4) * 8);
    const unsigned short* b0 = Wt_emb + (size_t)(n0 + w * 16 + (lane & 15)) * EE + ((lane >> 4) * 8);
    f32x4 acc[4];
#pragma unroll
    for (int mt = 0; mt < 4; ++mt) acc[mt] = (f32x4){0.f, 0.f, 0.f, 0.f};
    mmN<4, EE, EE>(a0, b0, acc);
    int n = n0 + w * 16 + (lane & 15);
    float bv = bih[n] + bhh[n];
#pragma unroll
    for (int mt = 0; mt < 4; ++mt)
#pragma unroll
        for (int r = 0; r < 4; ++r) {
            int m = mt * 16 + (lane >> 4) * 4 + r;
            embW[((size_t)tstep * 64 + m) * 2048 + n] = acc[mt][r] + bv;
        }
}

__global__ __launch_bounds__(256) void k_enattn_mfma(const unsigned short* __restrict__ enc_bf,
                                                     const unsigned short* __restrict__ Wt,
                                                     const float* __restrict__ bias,
                                                     unsigned short* __restrict__ en_bf) {
    int m0 = blockIdx.x * 64;
    int lane = threadIdx.x & 63, w = threadIdx.x >> 6;
    const unsigned short* a0 = enc_bf + (size_t)(m0 + (lane & 15)) * CC + ((lane >> 4) * 8);
    const unsigned short* bptr[8];
#pragma unroll
    for (int nt = 0; nt < 8; ++nt) {
        int rowB = nt * 64 + w * 16 + (lane & 15);
        bptr[nt] = Wt + (size_t)rowB * CC + ((lane >> 4) * 8);
    }
    f32x4 acc[4][8];
#pragma unroll
    for (int mt = 0; mt < 4; ++mt)
#pragma unroll
        for (int nt = 0; nt < 8; ++nt) acc[mt][nt] = (f32x4){0.f, 0.f, 0.f, 0.f};

    for (int kc = 0; kc < CC / 32; ++kc) {
        bf16x8 afr[4];
#pragma unroll
        for (int mt = 0; mt < 4; ++mt)
            afr[mt] = *reinterpret_cast<const bf16x8*>(a0 + (size_t)mt * 16 * CC + kc * 32);
#pragma unroll
        for (int nt = 0; nt < 8; ++nt) {
            bf16x8 bfr = *reinterpret_cast<const bf16x8*>(bptr[nt] + kc * 32);
#pragma unroll
            for (int mt = 0; mt < 4; ++mt)
                acc[mt][nt] = __builtin_amdgcn_mfma_f32_16x16x32_bf16(afr[mt], bfr, acc[mt][nt], 0, 0, 0);
        }
    }
#pragma unroll
    for (int nt = 0; nt < 8; ++nt) {
        int n = nt * 64 + w * 16 + (lane & 15);
        float bv = bias[n];
#pragma unroll
        for (int mt = 0; mt < 4; ++mt)
#pragma unroll
            for (int r = 0; r < 4; ++r) {
                int m = m0 + mt * 16 + (lane >> 4) * 4 + r;
                en_bf[(size_t)m * AA + n] = f2bf(acc[mt][nt][r] + bv);
            }
    }
}

// pre-loop: de (blocks 0..7) and gate-sigmoid (blocks 8..39) from initial h
__global__ __launch_bounds__(256) void k_pre0(const unsigned short* __restrict__ xh_bf,
                                              const unsigned short* __restrict__ Wt_de,
                                              const float* __restrict__ b_de,
                                              const unsigned short* __restrict__ Wt_gate,
                                              const float* __restrict__ b_gate,
                                              float* __restrict__ de, float* __restrict__ gsig) {
    int lane = threadIdx.x & 63, w = threadIdx.x >> 6;
    int l15 = lane & 15, hi = lane >> 4;
    const unsigned short* a0 = xh_bf + CC + (size_t)l15 * XH + hi * 8;
    f32x4 acc[4];
#pragma unroll
    for (int mt = 0; mt < 4; ++mt) acc[mt] = (f32x4){0.f, 0.f, 0.f, 0.f};
    if (blockIdx.x < 8) {
        int n0 = (blockIdx.x * 4 + w) * 16;
        const unsigned short* b0 = Wt_de + (size_t)(n0 + l15) * DD + hi * 8;
        mmN<4, DD, XH>(a0, b0, acc);
        int n = n0 + l15;
        float bv = b_de[n];
#pragma unroll
        for (int mt = 0; mt < 4; ++mt)
#pragma unroll
            for (int r = 0; r < 4; ++r) {
                int m = mt * 16 + hi * 4 + r;
                de[(size_t)m * AA + n] = acc[mt][r] + bv;
            }
    } else {
        int n0 = (blockIdx.x - 8) * 64 + w * 16;
        const unsigned short* b0 = Wt_gate + (size_t)(n0 + l15) * DD + hi * 8;
        mmN<4, DD, XH>(a0, b0, acc);
        int n = n0 + l15;
        float bv = b_gate[n];
#pragma unroll
        for (int mt = 0; mt < 4; ++mt)
#pragma unroll
            for (int r = 0; r < 4; ++r) {
                int m = mt * 16 + hi * 4 + r;
                gsig[(size_t)m * CC + n] = 1.f / (1.f + expf(-(acc[mt][r] + bv)));
            }
    }
}

// ---------- per-step kernels ----------

// fused score+softmax (redundant per y-block) + ctx slice + gate-multiply ; grid (64,4), block 256
__global__ __launch_bounds__(256) void k_actxg(const unsigned short* __restrict__ en_bf,
                                               const float* __restrict__ de,
                                               const float* __restrict__ Wat, const float* __restrict__ bat,
                                               const int* __restrict__ tlen, int t,
                                               const unsigned short* __restrict__ enc_bf,
                                               const float* __restrict__ gsig,
                                               unsigned short* __restrict__ xh_bf,
                                               float* __restrict__ out_attn) {
    int b = blockIdx.x;
    int tid = threadIdx.x;
    bool writer = (blockIdx.y == 0);
    if (t >= tlen[b]) {
        if (writer && tid < PP) out_attn[((size_t)b * TT + t) * PP + tid] = 0.f;
        return;
    }
    __shared__ float deL[AA];
    __shared__ float watL[AA];
    __shared__ float wred[4];
    __shared__ float al[PP];
    deL[tid] = de[(size_t)b * AA + tid];
    deL[tid + 256] = de[(size_t)b * AA + 256 + tid];
    watL[tid] = Wat[tid];
    watL[tid + 256] = Wat[tid + 256];
    __syncthreads();
    float s0 = 0.f, s1 = 0.f;
    if (tid < PP) {
        const unsigned short* er = en_bf + ((size_t)b * PP + tid) * AA;
#pragma unroll 2
        for (int a16 = 0; a16 < AA / 16; ++a16) {
            bf16x8 v0 = *reinterpret_cast<const bf16x8*>(er + a16 * 16);
            bf16x8 v1 = *reinterpret_cast<const bf16x8*>(er + a16 * 16 + 8);
#pragma unroll
            for (int j = 0; j < 8; ++j) {
                float u0 = fmaxf(bf2f((unsigned short)v0[j]) + deL[a16 * 16 + j], 0.f);
                float u1 = fmaxf(bf2f((unsigned short)v1[j]) + deL[a16 * 16 + 8 + j], 0.f);
                s0 = fmaf(u0, watL[a16 * 16 + j], s0);
                s1 = fmaf(u1, watL[a16 * 16 + 8 + j], s1);
            }
        }
    }
    float s = s0 + s1 + bat[0];
    int wid = tid >> 6;
    // wave-level max reduce (64 lanes), then 4-wave LDS combine
    float sv = (tid < PP) ? s : -3.4e38f;
#pragma unroll
    for (int off = 32; off; off >>= 1) sv = fmaxf(sv, __shfl_xor(sv, off));
    if ((tid & 63) == 0) wred[wid] = sv;
    __syncthreads();
    float m = fmaxf(fmaxf(wred[0], wred[1]), fmaxf(wred[2], wred[3]));
    float e = (tid < PP) ? expf(s - m) : 0.f;
    float ev = e;
#pragma unroll
    for (int off = 32; off; off >>= 1) ev += __shfl_xor(ev, off);
    __syncthreads();   // all reads of wred(max) done before overwrite
    if ((tid & 63) == 0) wred[wid] = ev;
    __syncthreads();
    float inv = 1.0f / (wred[0] + wred[1] + wred[2] + wred[3]);
    if (tid < PP) {
        float a_ = e * inv;
        al[tid] = a_;
        if (writer) out_attn[((size_t)b * TT + t) * PP + tid] = a_;
    }
    __syncthreads();
    // ctx slice: 64 c-lanes x 4 p-groups over this y-block's 512 columns
    int lane = tid & 63, pg = tid >> 6;
    int c0 = blockIdx.y * 512 + lane * 8;
    const unsigned short* img = enc_bf + (size_t)b * PP * CC + c0;
    float sa[8] = {0.f, 0.f, 0.f, 0.f, 0.f, 0.f, 0.f, 0.f};
    for (int p = pg; p < PP; p += 4) {
        float a = al[p];
        bf16x8 v = *reinterpret_cast<const bf16x8*>(img + (size_t)p * CC);
#pragma unroll
        for (int j = 0; j < 8; ++j) sa[j] = fmaf(a, bf2f((unsigned short)v[j]), sa[j]);
    }
    __shared__ float r8[4][512];
#pragma unroll
    for (int j = 0; j < 8; ++j) r8[pg][lane * 8 + j] = sa[j];
    __syncthreads();
#pragma unroll
    for (int cc = 0; cc < 2; ++cc) {
        int ci = tid + cc * 256;
        int c = blockIdx.y * 512 + ci;
        float tt = r8[0][ci] + r8[1][ci] + r8[2][ci] + r8[3][ci];
        xh_bf[(size_t)b * XH + c] = f2bf(tt * gsig[(size_t)b * CC + c]);
    }
}

// gates GEMM 8-wave split-K (wave = (gate, K-half)), LDS reduce, waves 0-3 LSTM ; grid 32, block 512
__global__ __launch_bounds__(512) void k_gateslstm(const unsigned short* __restrict__ xh_bf,
                                                   const unsigned short* __restrict__ Wt,
                                                   const float* __restrict__ embW,
                                                   const int* __restrict__ tlen, int t,
                                                   unsigned short* __restrict__ xh_out,
                                                   float* __restrict__ c_f32,
                                                   unsigned short* __restrict__ hn_bf) {
    int nAct = (int)(t < tlen[0]) + (int)(t < tlen[16]) + (int)(t < tlen[32]) + (int)(t < tlen[48]);
    if (nAct == 0) return;
    int tid = threadIdx.x, wid = tid >> 6, lane = tid & 63;
    int g = wid & 3, kh = wid >> 2;
    int col = lane & 15, hi = lane >> 4;
    int d0 = blockIdx.x * 16;
    const unsigned short* a0 = xh_bf + (size_t)col * XH + kh * (XH / 2) + hi * 8;
    const unsigned short* b0 = Wt + (size_t)(g * DD + d0 + col) * XH + kh * (XH / 2) + hi * 8;

    f32x4 acc[4];
    if (kh == 0) {
        const float* ew = embW + (size_t)t * 64 * 2048;
#pragma unroll
        for (int mt = 0; mt < 4; ++mt)
#pragma unroll
            for (int r = 0; r < 4; ++r) {
                int m = mt * 16 + hi * 4 + r;
                acc[mt][r] = ew[(size_t)m * 2048 + g * DD + d0 + col];
            }
    } else {
#pragma unroll
        for (int mt = 0; mt < 4; ++mt) acc[mt] = (f32x4){0.f, 0.f, 0.f, 0.f};
    }
    mmD<XH / 2, XH>(nAct, a0, b0, acc);

    __shared__ float lg[8][64][17];   // [wave][b][col], padded
#pragma unroll
    for (int mt = 0; mt < 4; ++mt)
#pragma unroll
        for (int r = 0; r < 4; ++r)
            lg[wid][mt * 16 + hi * 4 + r][col] = acc[mt][r];
    __syncthreads();

    // epilogue: wave `wid` (0..3) handles m-tile `wid`, summing the two K-halves
    if (wid < nAct) {
        int d = d0 + col;
#pragma unroll
        for (int r = 0; r < 4; ++r) {
            int b = wid * 16 + hi * 4 + r;
            float iv = lg[0][b][col] + lg[4][b][col];
            float fv = lg[1][b][col] + lg[5][b][col];
            float gv = lg[2][b][col] + lg[6][b][col];
            float ov = lg[3][b][col] + lg[7][b][col];
            float cv = c_f32[(size_t)b * DD + d];
            float si = 1.f / (1.f + expf(-iv));
            float sf = 1.f / (1.f + expf(-fv));
            float so = 1.f / (1.f + expf(-ov));
            float cn = sf * cv + si * tanhf(gv);
            float hn = so * tanhf(cn);
            hn_bf[(size_t)b * DD + d] = f2bf(hn);
            if (t < tlen[b]) {
                xh_out[(size_t)b * XH + CC + d] = f2bf(hn);
                c_f32[(size_t)b * DD + d] = cn;
            }
        }
    }
}

// head (0..468) + next-step de (469..476) + next-step gate-sigmoid (477..508)
__global__ __launch_bounds__(256) void k_head_de_gate(const unsigned short* __restrict__ hn_bf,
                                                      const unsigned short* __restrict__ Wt_head,
                                                      const float* __restrict__ b_head,
                                                      const unsigned short* __restrict__ xh_bf,
                                                      const unsigned short* __restrict__ Wt_de,
                                                      const float* __restrict__ b_de,
                                                      const unsigned short* __restrict__ Wt_gate,
                                                      const float* __restrict__ b_gate,
                                                      const int* __restrict__ tlen, int t,
                                                      float* __restrict__ out_pred,
                                                      float* __restrict__ de, float* __restrict__ gsig) {
    int lane = threadIdx.x & 63, w = threadIdx.x >> 6;
    int l15 = lane & 15, hi = lane >> 4;
    f32x4 acc[4];
#pragma unroll
    for (int mt = 0; mt < 4; ++mt) acc[mt] = (f32x4){0.f, 0.f, 0.f, 0.f};
    if (blockIdx.x < HEADBLK) {
        int nAct = (int)(t < tlen[0]) + (int)(t < tlen[16]) + (int)(t < tlen[32]) + (int)(t < tlen[48]);
        int n0 = blockIdx.x * 64;
        const unsigned short* a0 = hn_bf + (size_t)l15 * DD + hi * 8;
        const unsigned short* b0 = Wt_head + (size_t)(n0 + w * 16 + l15) * DD + hi * 8;
        mmD<DD, DD>(nAct, a0, b0, acc);
        int v = n0 + w * 16 + l15;
        if (v >= VV) return;
        float bv = b_head[v];
#pragma unroll
        for (int mt = 0; mt < 4; ++mt)
#pragma unroll
            for (int r = 0; r < 4; ++r) {
                int b = mt * 16 + hi * 4 + r;
                bool a = t < tlen[b];
                out_pred[(size_t)b * TT * VV + (size_t)t * VV + v] = a ? (acc[mt][r] + bv) : 0.f;
            }
    } else if (blockIdx.x < HEADBLK + 8) {
        int nAct = (int)(t + 1 < tlen[0]) + (int)(t + 1 < tlen[16]) + (int)(t + 1 < tlen[32]) + (int)(t + 1 < tlen[48]);
        int n0 = ((blockIdx.x - HEADBLK) * 4 + w) * 16;
        const unsigned short* a0 = xh_bf + CC + (size_t)l15 * XH + hi * 8;
        const unsigned short* b0 = Wt_de + (size_t)(n0 + l15) * DD + hi * 8;
        mmD<DD, XH>(nAct, a0, b0, acc);
        int n = n0 + l15;
        float bv = b_de[n];
#pragma unroll
        for (int mt = 0; mt < 4; ++mt)
#pragma unroll
            for (int r = 0; r < 4; ++r) {
                int m = mt * 16 + hi * 4 + r;
                de[(size_t)m * AA + n] = acc[mt][r] + bv;
            }
    } else {
        int nAct = (int)(t + 1 < tlen[0]) + (int)(t + 1 < tlen[16]) + (int)(t + 1 < tlen[32]) + (int)(t + 1 < tlen[48]);
        int n0 = (blockIdx.x - HEADBLK - 8) * 64 + w * 16;
        const unsigned short* a0 = xh_bf + CC + (size_t)l15 * XH + hi * 8;
        const unsigned short* b0 = Wt_gate + (size_t)(n0 + l15) * DD + hi * 8;
        mmD<DD, XH>(nAct, a0, b0, acc);
        int n = n0 + l15;
        float bv = b_gate[n];
#pragma unroll
        for (int mt = 0; mt < 4; ++mt)
#pragma unroll
            for (int r = 0; r < 4; ++r) {
                int m = mt * 16 + hi * 4 + r;
                gsig[(size_t)m * CC + n] = 1.f / (1.f + expf(-(acc[mt][r] + bv)));
            }
    }
}

extern "C" void kernel_launch(void* const* d_in, const int* in_sizes, int n_in,
                              void* d_out, int out_size, void* d_ws, size_t ws_size,
                              hipStream_t stream) {
    const float* enc     = (const float*)d_in[0];
    const int*   text    = (const int*)d_in[1];
    const int*   lens    = (const int*)d_in[2];
    const float* W_init_h = (const float*)d_in[3];
    const float* b_init_h = (const float*)d_in[4];
    const float* W_init_c = (const float*)d_in[5];
    const float* b_init_c = (const float*)d_in[6];
    const float* W_en    = (const float*)d_in[7];
    const float* b_en    = (const float*)d_in[8];
    const float* W_de    = (const float*)d_in[9];
    const float* b_de    = (const float*)d_in[10];
    const float* W_at    = (const float*)d_in[11];
    const float* b_at    = (const float*)d_in[12];
    const float* W_gate  = (const float*)d_in[13];
    const float* b_gate  = (const float*)d_in[14];
    const float* W_ih    = (const float*)d_in[15];
    const float* b_ih    = (const float*)d_in[16];
    const float* W_hh    = (const float*)d_in[17];
    const float* b_hh    = (const float*)d_in[18];
    const float* embed   = (const float*)d_in[19];
    const float* W_head  = (const float*)d_in[20];
    const float* b_head  = (const float*)d_in[21];

    float* outf = (float*)d_out;
    float* out_pred = outf;                               // B*T*V
    float* out_text = outf + (size_t)BB * TT * VV;        // B*L
    float* out_tlen = out_text + BB * LL;                 // B
    float* out_attn = out_tlen + BB;                      // B*T*P
    float* out_idx  = out_attn + (size_t)BB * TT * PP;    // B

    // ---- workspace layout ----
    char* wsb = (char*)d_ws;
    int* idx  = (int*)wsb;
    int* inv  = idx + 64;
    int* tlen = inv + 64;
    int* ts   = tlen + 64;              // 64*32
    float* fw = (float*)(wsb + 16384);
    float* c_f32 = fw;  fw += (size_t)BB * DD;
    float* de    = fw;  fw += (size_t)BB * AA;
    float* gsig  = fw;  fw += (size_t)BB * CC;
    float* embW  = fw;  fw += (size_t)TT * BB * 2048;
    unsigned short* us = (unsigned short*)fw;
    unsigned short* mean_bf = us;  us += (size_t)BB * CC;
    unsigned short* xh_bf   = us;  us += (size_t)BB * XH;
    unsigned short* hn_bf   = us;  us += (size_t)BB * DD;
    unsigned short* emb_all = us;  us += (size_t)TT * BB * EE;
    unsigned short* en_bf   = us;  us += (size_t)BB * PP * AA;
    unsigned short* enc_bf  = us;  us += (size_t)BB * PP * CC;
    unsigned short* Wt_en   = us;  us += (size_t)AA * CC;
    unsigned short* Wt_de   = us;  us += (size_t)AA * DD;
    unsigned short* Wt_gate = us;  us += (size_t)CC * DD;
    unsigned short* Wt_emb  = us;  us += (size_t)2048 * EE;
    unsigned short* Wt_ihh  = us;  us += (size_t)2048 * XH;
    unsigned short* Wt_ih0  = us;  us += (size_t)DD * CC;
    unsigned short* Wt_ic0  = us;  us += (size_t)DD * CC;
    unsigned short* Wt_head = us;  us += (size_t)VPAD * DD;

    // ---- setup ----
    k_sort<<<1, 64, 0, stream>>>(text, lens, idx, inv, tlen, ts, out_text, out_tlen, out_idx);
    k_cvtenc<<<BB * PP, 256, 0, stream>>>(enc, idx, enc_bf);
    k_meanbf<<<dim3(BB, CC / 256), 256, 0, stream>>>(enc_bf, inv, mean_bf);

    dim3 tb(32, 8);
    k_transcvt<<<dim3(AA / 32, CC / 32), tb, 0, stream>>>(W_en, CC, AA, Wt_en, CC, AA);
    k_transcvt<<<dim3(AA / 32, DD / 32), tb, 0, stream>>>(W_de, DD, AA, Wt_de, DD, AA);
    k_transcvt<<<dim3(CC / 32, DD / 32), tb, 0, stream>>>(W_gate, DD, CC, Wt_gate, DD, CC);
    k_transcvt<<<dim3(CC / 32, CC / 32), tb, 0, stream>>>(W_ih, CC, 2048, Wt_ihh, XH, 2048);
    k_transcvt<<<dim3(CC / 32, DD / 32), tb, 0, stream>>>(W_hh, DD, 2048, Wt_ihh + CC, XH, 2048);
    k_transcvt<<<dim3(CC / 32, DD / 32), tb, 0, stream>>>(W_ih + (size_t)CC * 2048, DD, 2048, Wt_emb, EE, 2048);
    k_transcvt<<<dim3(DD / 32, CC / 32), tb, 0, stream>>>(W_init_h, CC, DD, Wt_ih0, CC, DD);
    k_transcvt<<<dim3(DD / 32, CC / 32), tb, 0, stream>>>(W_init_c, CC, DD, Wt_ic0, CC, DD);
    k_transcvt<<<dim3(VPAD / 32, DD / 32), tb, 0, stream>>>(W_head, DD, VV, Wt_head, DD, VPAD);

    k_init_mfma<<<64, 64, 0, stream>>>(mean_bf, Wt_ih0, Wt_ic0, b_init_h, b_init_c, xh_bf, c_f32);
    k_emball<<<TT * BB, 256, 0, stream>>>(embed, ts, emb_all);
    k_embw<<<dim3(TT, 2048 / 64), 256, 0, stream>>>(emb_all, Wt_emb, b_ih, b_hh, embW);
    k_enattn_mfma<<<PP, 256, 0, stream>>>(enc_bf, Wt_en, b_en, en_bf);
    k_pre0<<<40, 256, 0, stream>>>(xh_bf, Wt_de, b_de, Wt_gate, b_gate, de, gsig);

    // ---- decode loop: 3 launches/step ----
    for (int t = 0; t < TT; ++t) {
        k_actxg<<<dim3(BB, 4), 256, 0, stream>>>(en_bf, de, W_at, b_at, tlen, t, enc_bf, gsig, xh_bf, out_attn);
        k_gateslstm<<<DD / 16, 512, 0, stream>>>(xh_bf, Wt_ihh, embW, tlen, t, xh_bf, c_f32, hn_bf);
        k_head_de_gate<<<HEADBLK + 40, 256, 0, stream>>>(hn_bf, Wt_head, b_head, xh_bf, Wt_de, b_de,
                                                         Wt_gate, b_gate, tlen, t, out_pred, de, gsig);
    }
}

// Round 12
// 2666.805 us; speedup vs baseline: 1.0353x; 1.0353x over previous
//
#include <hip/hip_runtime.h>
#include <hip/hip_bf16.h>
#include <math.h>

#define BB 64
#define PP 196
#define CC 2048
#define DD 512
#define AA 512
#define EE 512
#define VV 30000
#define VPAD 30016
#define LL 32
#define TT 31
#define XH 2560      // [ctx*gate (2048) | h (512)]
#define HEADBLK 469  // VPAD/64

typedef short bf16x8 __attribute__((ext_vector_type(8)));
typedef float f32x4 __attribute__((ext_vector_type(4)));

__device__ inline unsigned short f2bf(float x) {
    __hip_bfloat16 h = __float2bfloat16(x);
    return __builtin_bit_cast(unsigned short, h);
}
__device__ inline float bf2f(unsigned short u) {
    unsigned int x = ((unsigned int)u) << 16;
    return __builtin_bit_cast(float, x);
}

// MFMA core over first NA m-tiles — branch-free, fully unrolled per instantiation.
template<int NA, int K, int LDA>
__device__ inline void mmN(const unsigned short* __restrict__ a0,
                           const unsigned short* __restrict__ b0,
                           f32x4 acc[4]) {
#pragma unroll
    for (int kc = 0; kc < K / 32; ++kc) {
        bf16x8 bfr = *reinterpret_cast<const bf16x8*>(b0 + kc * 32);
#pragma unroll
        for (int mt = 0; mt < NA; ++mt) {
            bf16x8 afr = *reinterpret_cast<const bf16x8*>(a0 + (size_t)mt * 16 * LDA + kc * 32);
            acc[mt] = __builtin_amdgcn_mfma_f32_16x16x32_bf16(afr, bfr, acc[mt], 0, 0, 0);
        }
    }
}

// uniform dispatch on active-tile count (prefix pattern)
template<int K, int LDA>
__device__ inline void mmD(int nAct, const unsigned short* __restrict__ a0,
                           const unsigned short* __restrict__ b0, f32x4 acc[4]) {
    switch (nAct) {
        case 4: mmN<4, K, LDA>(a0, b0, acc); break;
        case 3: mmN<3, K, LDA>(a0, b0, acc); break;
        case 2: mmN<2, K, LDA>(a0, b0, acc); break;
        case 1: mmN<1, K, LDA>(a0, b0, acc); break;
        default: break;
    }
}

// ---------- setup kernels ----------

__global__ void k_sort(const int* __restrict__ text, const int* __restrict__ lens,
                       int* __restrict__ idx, int* __restrict__ inv, int* __restrict__ tlen,
                       int* __restrict__ ts,
                       float* __restrict__ out_text, float* __restrict__ out_tlen,
                       float* __restrict__ out_idx) {
    int j = threadIdx.x;
    __shared__ int key[BB];
    __shared__ int sidx[BB];
    key[j] = lens[j];
    __syncthreads();
    int kj = key[j];
    int pos = 0;
    for (int q = 0; q < BB; ++q) {
        int kq = key[q];
        if (kq > kj || (kq == kj && q < j)) pos++;
    }
    sidx[pos] = j;
    __syncthreads();
    int src = sidx[j];
    idx[j] = src;
    inv[src] = j;
    int tl = key[src] - 1;
    tlen[j] = tl;
    out_idx[j] = (float)src;
    out_tlen[j] = (float)tl;
    for (int l = 0; l < LL; ++l) {
        int tok = text[src * LL + l];
        ts[j * LL + l] = tok;
        out_text[j * LL + l] = (float)tok;
    }
}

__global__ __launch_bounds__(256) void k_cvtenc(const float* __restrict__ enc, const int* __restrict__ idx,
                                                unsigned short* __restrict__ enc_bf) {
    int row = blockIdx.x;           // bs*196+p
    int bs = row / PP, p = row - bs * PP;
    int c0 = threadIdx.x * 8;
    const float* src = enc + ((size_t)idx[bs] * PP + p) * CC + c0;
    f32x4 lo = *reinterpret_cast<const f32x4*>(src);
    f32x4 hi = *reinterpret_cast<const f32x4*>(src + 4);
    unsigned short* dst = enc_bf + (size_t)row * CC + c0;
    bf16x8 v;
    v[0] = (short)f2bf(lo[0]); v[1] = (short)f2bf(lo[1]);
    v[2] = (short)f2bf(lo[2]); v[3] = (short)f2bf(lo[3]);
    v[4] = (short)f2bf(hi[0]); v[5] = (short)f2bf(hi[1]);
    v[6] = (short)f2bf(hi[2]); v[7] = (short)f2bf(hi[3]);
    *reinterpret_cast<bf16x8*>(dst) = v;
}

__global__ __launch_bounds__(256) void k_meanbf(const unsigned short* __restrict__ enc_bf,
                                                const int* __restrict__ inv,
                                                unsigned short* __restrict__ mean_bf) {
    int b = blockIdx.x;
    int lane = threadIdx.x & 31, pg = threadIdx.x >> 5;
    int c0 = blockIdx.y * 256 + lane * 8;
    const unsigned short* img = enc_bf + (size_t)inv[b] * PP * CC + c0;
    float s[8] = {0.f, 0.f, 0.f, 0.f, 0.f, 0.f, 0.f, 0.f};
    for (int p = pg; p < PP; p += 8) {
        bf16x8 v = *reinterpret_cast<const bf16x8*>(img + (size_t)p * CC);
#pragma unroll
        for (int j = 0; j < 8; ++j) s[j] += bf2f((unsigned short)v[j]);
    }
    __shared__ float red[8][256];
#pragma unroll
    for (int j = 0; j < 8; ++j) red[pg][lane * 8 + j] = s[j];
    __syncthreads();
    int c = threadIdx.x;
    float tt = 0.f;
#pragma unroll
    for (int g = 0; g < 8; ++g) tt += red[g][c];
    mean_bf[(size_t)b * CC + blockIdx.y * 256 + c] = f2bf(tt * (1.0f / PP));
}

__global__ __launch_bounds__(64) void k_init_mfma(const unsigned short* __restrict__ mean_bf,
                                                  const unsigned short* __restrict__ Wt_ih,
                                                  const unsigned short* __restrict__ Wt_ic,
                                                  const float* __restrict__ bh, const float* __restrict__ bc,
                                                  unsigned short* __restrict__ xh_bf, float* __restrict__ c_f32) {
    int isC = blockIdx.x >= 32;
    int n0 = (blockIdx.x & 31) * 16;
    int lane = threadIdx.x;
    const unsigned short* Wt = isC ? Wt_ic : Wt_ih;
    const unsigned short* a0 = mean_bf + (size_t)(lane & 15) * CC + ((lane >> 4) * 8);
    const unsigned short* b0 = Wt + (size_t)(n0 + (lane & 15)) * CC + ((lane >> 4) * 8);
    f32x4 acc[4];
#pragma unroll
    for (int mt = 0; mt < 4; ++mt) acc[mt] = (f32x4){0.f, 0.f, 0.f, 0.f};
    mmN<4, CC, CC>(a0, b0, acc);
    int n = n0 + (lane & 15);
    float bv = (isC ? bc : bh)[n];
#pragma unroll
    for (int mt = 0; mt < 4; ++mt)
#pragma unroll
        for (int r = 0; r < 4; ++r) {
            int m = mt * 16 + (lane >> 4) * 4 + r;
            float val = acc[mt][r] + bv;
            if (isC) c_f32[(size_t)m * DD + n] = val;
            else     xh_bf[(size_t)m * XH + CC + n] = f2bf(val);
        }
}

__global__ __launch_bounds__(256) void k_transcvt(const float* __restrict__ src, int K, int N,
                                                  unsigned short* __restrict__ dst, int dstStride, int Npad) {
    __shared__ float t[32][33];
    int n0 = blockIdx.x * 32, k0 = blockIdx.y * 32;
    int tx = threadIdx.x, ty = threadIdx.y;
#pragma unroll
    for (int r = 0; r < 4; ++r) {
        int k = k0 + ty + r * 8;
        int n = n0 + tx;
        t[ty + r * 8][tx] = (n < N) ? src[(size_t)k * N + n] : 0.f;
    }
    __syncthreads();
#pragma unroll
    for (int r = 0; r < 4; ++r) {
        int n = n0 + ty + r * 8;
        int k = k0 + tx;
        if (n < Npad) dst[(size_t)n * dstStride + k] = f2bf(t[tx][ty + r * 8]);
    }
}

__global__ __launch_bounds__(256) void k_emball(const float* __restrict__ embed, const int* __restrict__ ts,
                                                unsigned short* __restrict__ emb_all) {
    int row = blockIdx.x;           // t*64+b
    int t = row >> 6, b = row & 63;
    int tok = ts[b * LL + t];
    int e = threadIdx.x * 2;
    const float* src = embed + (size_t)tok * EE + e;
    unsigned short* dst = emb_all + (size_t)row * EE + e;
    dst[0] = f2bf(src[0]);
    dst[1] = f2bf(src[1]);
}

__global__ __launch_bounds__(256) void k_embw(const unsigned short* __restrict__ emb_all,
                                              const unsigned short* __restrict__ Wt_emb,
                                              const float* __restrict__ bih, const float* __restrict__ bhh,
                                              float* __restrict__ embW) {
    int tstep = blockIdx.x;
    int n0 = blockIdx.y * 64;
    int lane = threadIdx.x & 63, w = threadIdx.x >> 6;
    const unsigned short* a0 = emb_all + ((size_t)tstep * 64 + (lane & 15)) * EE + ((lane >> 4) * 8);
    const unsigned short* b0 = Wt_emb + (size_t)(n0 + w * 16 + (lane & 15)) * EE + ((lane >> 4) * 8);
    f32x4 acc[4];
#pragma unroll
    for (int mt = 0; mt < 4; ++mt) acc[mt] = (f32x4){0.f, 0.f, 0.f, 0.f};
    mmN<4, EE, EE>(a0, b0, acc);
    int n = n0 + w * 16 + (lane & 15);
    float bv = bih[n] + bhh[n];
#pragma unroll
    for (int mt = 0; mt < 4; ++mt)
#pragma unroll
        for (int r = 0; r < 4; ++r) {
            int m = mt * 16 + (lane >> 4) * 4 + r;
            embW[((size_t)tstep * 64 + m) * 2048 + n] = acc[mt][r] + bv;
        }
}

__global__ __launch_bounds__(256) void k_enattn_mfma(const unsigned short* __restrict__ enc_bf,
                                                     const unsigned short* __restrict__ Wt,
                                                     const float* __restrict__ bias,
                                                     unsigned short* __restrict__ en_bf) {
    int m0 = blockIdx.x * 64;
    int lane = threadIdx.x & 63, w = threadIdx.x >> 6;
    const unsigned short* a0 = enc_bf + (size_t)(m0 + (lane & 15)) * CC + ((lane >> 4) * 8);
    const unsigned short* bptr[8];
#pragma unroll
    for (int nt = 0; nt < 8; ++nt) {
        int rowB = nt * 64 + w * 16 + (lane & 15);
        bptr[nt] = Wt + (size_t)rowB * CC + ((lane >> 4) * 8);
    }
    f32x4 acc[4][8];
#pragma unroll
    for (int mt = 0; mt < 4; ++mt)
#pragma unroll
        for (int nt = 0; nt < 8; ++nt) acc[mt][nt] = (f32x4){0.f, 0.f, 0.f, 0.f};

    for (int kc = 0; kc < CC / 32; ++kc) {
        bf16x8 afr[4];
#pragma unroll
        for (int mt = 0; mt < 4; ++mt)
            afr[mt] = *reinterpret_cast<const bf16x8*>(a0 + (size_t)mt * 16 * CC + kc * 32);
#pragma unroll
        for (int nt = 0; nt < 8; ++nt) {
            bf16x8 bfr = *reinterpret_cast<const bf16x8*>(bptr[nt] + kc * 32);
#pragma unroll
            for (int mt = 0; mt < 4; ++mt)
                acc[mt][nt] = __builtin_amdgcn_mfma_f32_16x16x32_bf16(afr[mt], bfr, acc[mt][nt], 0, 0, 0);
        }
    }
#pragma unroll
    for (int nt = 0; nt < 8; ++nt) {
        int n = nt * 64 + w * 16 + (lane & 15);
        float bv = bias[n];
#pragma unroll
        for (int mt = 0; mt < 4; ++mt)
#pragma unroll
            for (int r = 0; r < 4; ++r) {
                int m = m0 + mt * 16 + (lane >> 4) * 4 + r;
                en_bf[(size_t)m * AA + n] = f2bf(acc[mt][nt][r] + bv);
            }
    }
}

// pre-loop: de (blocks 0..7) and gate-sigmoid (blocks 8..39) from initial h
__global__ __launch_bounds__(256) void k_pre0(const unsigned short* __restrict__ xh_bf,
                                              const unsigned short* __restrict__ Wt_de,
                                              const float* __restrict__ b_de,
                                              const unsigned short* __restrict__ Wt_gate,
                                              const float* __restrict__ b_gate,
                                              float* __restrict__ de, float* __restrict__ gsig) {
    int lane = threadIdx.x & 63, w = threadIdx.x >> 6;
    int l15 = lane & 15, hi = lane >> 4;
    const unsigned short* a0 = xh_bf + CC + (size_t)l15 * XH + hi * 8;
    f32x4 acc[4];
#pragma unroll
    for (int mt = 0; mt < 4; ++mt) acc[mt] = (f32x4){0.f, 0.f, 0.f, 0.f};
    if (blockIdx.x < 8) {
        int n0 = (blockIdx.x * 4 + w) * 16;
        const unsigned short* b0 = Wt_de + (size_t)(n0 + l15) * DD + hi * 8;
        mmN<4, DD, XH>(a0, b0, acc);
        int n = n0 + l15;
        float bv = b_de[n];
#pragma unroll
        for (int mt = 0; mt < 4; ++mt)
#pragma unroll
            for (int r = 0; r < 4; ++r) {
                int m = mt * 16 + hi * 4 + r;
                de[(size_t)m * AA + n] = acc[mt][r] + bv;
            }
    } else {
        int n0 = (blockIdx.x - 8) * 64 + w * 16;
        const unsigned short* b0 = Wt_gate + (size_t)(n0 + l15) * DD + hi * 8;
        mmN<4, DD, XH>(a0, b0, acc);
        int n = n0 + l15;
        float bv = b_gate[n];
#pragma unroll
        for (int mt = 0; mt < 4; ++mt)
#pragma unroll
            for (int r = 0; r < 4; ++r) {
                int m = mt * 16 + hi * 4 + r;
                gsig[(size_t)m * CC + n] = 1.f / (1.f + expf(-(acc[mt][r] + bv)));
            }
    }
}

// ---------- per-step kernels ----------

// fused score+softmax (redundant per y-block) + ctx slice + gate-multiply ; grid (64,8), block 256
__global__ __launch_bounds__(256) void k_actxg(const unsigned short* __restrict__ en_bf,
                                               const float* __restrict__ de,
                                               const float* __restrict__ Wat, const float* __restrict__ bat,
                                               const int* __restrict__ tlen, int t,
                                               const unsigned short* __restrict__ enc_bf,
                                               const float* __restrict__ gsig,
                                               unsigned short* __restrict__ xh_bf,
                                               float* __restrict__ out_attn) {
    int b = blockIdx.x;
    int tid = threadIdx.x;
    bool writer = (blockIdx.y == 0);
    if (t >= tlen[b]) {
        if (writer && tid < PP) out_attn[((size_t)b * TT + t) * PP + tid] = 0.f;
        return;
    }
    __shared__ float deL[AA];
    __shared__ float watL[AA];
    __shared__ float red[256];
    __shared__ float al[PP];
    deL[tid] = de[(size_t)b * AA + tid];
    deL[tid + 256] = de[(size_t)b * AA + 256 + tid];
    watL[tid] = Wat[tid];
    watL[tid + 256] = Wat[tid + 256];
    __syncthreads();
    float s0 = 0.f, s1 = 0.f;
    if (tid < PP) {
        const unsigned short* er = en_bf + ((size_t)b * PP + tid) * AA;
#pragma unroll 2
        for (int a16 = 0; a16 < AA / 16; ++a16) {
            bf16x8 v0 = *reinterpret_cast<const bf16x8*>(er + a16 * 16);
            bf16x8 v1 = *reinterpret_cast<const bf16x8*>(er + a16 * 16 + 8);
#pragma unroll
            for (int j = 0; j < 8; ++j) {
                float u0 = fmaxf(bf2f((unsigned short)v0[j]) + deL[a16 * 16 + j], 0.f);
                float u1 = fmaxf(bf2f((unsigned short)v1[j]) + deL[a16 * 16 + 8 + j], 0.f);
                s0 = fmaf(u0, watL[a16 * 16 + j], s0);
                s1 = fmaf(u1, watL[a16 * 16 + 8 + j], s1);
            }
        }
    }
    float s = s0 + s1 + bat[0];
    red[tid] = (tid < PP) ? s : -3.4e38f;
    __syncthreads();
    for (int st = 128; st > 0; st >>= 1) {
        if (tid < st) red[tid] = fmaxf(red[tid], red[tid + st]);
        __syncthreads();
    }
    float m = red[0];
    __syncthreads();
    float e = (tid < PP) ? expf(s - m) : 0.f;
    red[tid] = e;
    __syncthreads();
    for (int st = 128; st > 0; st >>= 1) {
        if (tid < st) red[tid] += red[tid + st];
        __syncthreads();
    }
    float inv = 1.0f / red[0];
    if (tid < PP) {
        float a_ = e * inv;
        al[tid] = a_;
        if (writer) out_attn[((size_t)b * TT + t) * PP + tid] = a_;
    }
    __syncthreads();
    // ctx slice: 32 c-lanes x 8 p-groups over this y-block's 256 columns
    int lane = tid & 31, pg = tid >> 5;
    int c0 = blockIdx.y * 256 + lane * 8;
    const unsigned short* img = enc_bf + (size_t)b * PP * CC + c0;
    float sa[8] = {0.f, 0.f, 0.f, 0.f, 0.f, 0.f, 0.f, 0.f};
    for (int p = pg; p < PP; p += 8) {
        float a = al[p];
        bf16x8 v = *reinterpret_cast<const bf16x8*>(img + (size_t)p * CC);
#pragma unroll
        for (int j = 0; j < 8; ++j) sa[j] = fmaf(a, bf2f((unsigned short)v[j]), sa[j]);
    }
    __shared__ float r8[8][256];
#pragma unroll
    for (int j = 0; j < 8; ++j) r8[pg][lane * 8 + j] = sa[j];
    __syncthreads();
    int c = blockIdx.y * 256 + tid;
    float tt = 0.f;
#pragma unroll
    for (int g = 0; g < 8; ++g) tt += r8[g][tid];
    xh_bf[(size_t)b * XH + c] = f2bf(tt * gsig[(size_t)b * CC + c]);
}

// gates GEMM 8-wave split-K (wave = (gate, K-half)), LDS reduce, waves 0-3 LSTM ; grid 32, block 512
__global__ __launch_bounds__(512) void k_gateslstm(const unsigned short* __restrict__ xh_bf,
                                                   const unsigned short* __restrict__ Wt,
                                                   const float* __restrict__ embW,
                                                   const int* __restrict__ tlen, int t,
                                                   unsigned short* __restrict__ xh_out,
                                                   float* __restrict__ c_f32,
                                                   unsigned short* __restrict__ hn_bf) {
    int nAct = (int)(t < tlen[0]) + (int)(t < tlen[16]) + (int)(t < tlen[32]) + (int)(t < tlen[48]);
    if (nAct == 0) return;
    int tid = threadIdx.x, wid = tid >> 6, lane = tid & 63;
    int g = wid & 3, kh = wid >> 2;
    int col = lane & 15, hi = lane >> 4;
    int d0 = blockIdx.x * 16;
    const unsigned short* a0 = xh_bf + (size_t)col * XH + kh * (XH / 2) + hi * 8;
    const unsigned short* b0 = Wt + (size_t)(g * DD + d0 + col) * XH + kh * (XH / 2) + hi * 8;

    f32x4 acc[4];
    if (kh == 0) {
        const float* ew = embW + (size_t)t * 64 * 2048;
#pragma unroll
        for (int mt = 0; mt < 4; ++mt)
#pragma unroll
            for (int r = 0; r < 4; ++r) {
                int m = mt * 16 + hi * 4 + r;
                acc[mt][r] = ew[(size_t)m * 2048 + g * DD + d0 + col];
            }
    } else {
#pragma unroll
        for (int mt = 0; mt < 4; ++mt) acc[mt] = (f32x4){0.f, 0.f, 0.f, 0.f};
    }
    mmD<XH / 2, XH>(nAct, a0, b0, acc);

    __shared__ float lg[8][64][17];   // [wave][b][col], padded
#pragma unroll
    for (int mt = 0; mt < 4; ++mt)
#pragma unroll
        for (int r = 0; r < 4; ++r)
            lg[wid][mt * 16 + hi * 4 + r][col] = acc[mt][r];
    __syncthreads();

    // epilogue: wave `wid` (0..3) handles m-tile `wid`, summing the two K-halves
    if (wid < nAct) {
        int d = d0 + col;
#pragma unroll
        for (int r = 0; r < 4; ++r) {
            int b = wid * 16 + hi * 4 + r;
            float iv = lg[0][b][col] + lg[4][b][col];
            float fv = lg[1][b][col] + lg[5][b][col];
            float gv = lg[2][b][col] + lg[6][b][col];
            float ov = lg[3][b][col] + lg[7][b][col];
            float cv = c_f32[(size_t)b * DD + d];
            float si = 1.f / (1.f + expf(-iv));
            float sf = 1.f / (1.f + expf(-fv));
            float so = 1.f / (1.f + expf(-ov));
            float cn = sf * cv + si * tanhf(gv);
            float hn = so * tanhf(cn);
            hn_bf[(size_t)b * DD + d] = f2bf(hn);
            if (t < tlen[b]) {
                xh_out[(size_t)b * XH + CC + d] = f2bf(hn);
                c_f32[(size_t)b * DD + d] = cn;
            }
        }
    }
}

// head (0..468) + next-step de (469..476) + next-step gate-sigmoid (477..508)
__global__ __launch_bounds__(256) void k_head_de_gate(const unsigned short* __restrict__ hn_bf,
                                                      const unsigned short* __restrict__ Wt_head,
                                                      const float* __restrict__ b_head,
                                                      const unsigned short* __restrict__ xh_bf,
                                                      const unsigned short* __restrict__ Wt_de,
                                                      const float* __restrict__ b_de,
                                                      const unsigned short* __restrict__ Wt_gate,
                                                      const float* __restrict__ b_gate,
                                                      const int* __restrict__ tlen, int t,
                                                      float* __restrict__ out_pred,
                                                      float* __restrict__ de, float* __restrict__ gsig) {
    int lane = threadIdx.x & 63, w = threadIdx.x >> 6;
    int l15 = lane & 15, hi = lane >> 4;
    f32x4 acc[4];
#pragma unroll
    for (int mt = 0; mt < 4; ++mt) acc[mt] = (f32x4){0.f, 0.f, 0.f, 0.f};
    if (blockIdx.x < HEADBLK) {
        int nAct = (int)(t < tlen[0]) + (int)(t < tlen[16]) + (int)(t < tlen[32]) + (int)(t < tlen[48]);
        int n0 = blockIdx.x * 64;
        const unsigned short* a0 = hn_bf + (size_t)l15 * DD + hi * 8;
        const unsigned short* b0 = Wt_head + (size_t)(n0 + w * 16 + l15) * DD + hi * 8;
        mmD<DD, DD>(nAct, a0, b0, acc);
        int v = n0 + w * 16 + l15;
        if (v >= VV) return;
        float bv = b_head[v];
#pragma unroll
        for (int mt = 0; mt < 4; ++mt)
#pragma unroll
            for (int r = 0; r < 4; ++r) {
                int b = mt * 16 + hi * 4 + r;
                bool a = t < tlen[b];
                out_pred[(size_t)b * TT * VV + (size_t)t * VV + v] = a ? (acc[mt][r] + bv) : 0.f;
            }
    } else if (blockIdx.x < HEADBLK + 8) {
        int nAct = (int)(t + 1 < tlen[0]) + (int)(t + 1 < tlen[16]) + (int)(t + 1 < tlen[32]) + (int)(t + 1 < tlen[48]);
        int n0 = ((blockIdx.x - HEADBLK) * 4 + w) * 16;
        const unsigned short* a0 = xh_bf + CC + (size_t)l15 * XH + hi * 8;
        const unsigned short* b0 = Wt_de + (size_t)(n0 + l15) * DD + hi * 8;
        mmD<DD, XH>(nAct, a0, b0, acc);
        int n = n0 + l15;
        float bv = b_de[n];
#pragma unroll
        for (int mt = 0; mt < 4; ++mt)
#pragma unroll
            for (int r = 0; r < 4; ++r) {
                int m = mt * 16 + hi * 4 + r;
                de[(size_t)m * AA + n] = acc[mt][r] + bv;
            }
    } else {
        int nAct = (int)(t + 1 < tlen[0]) + (int)(t + 1 < tlen[16]) + (int)(t + 1 < tlen[32]) + (int)(t + 1 < tlen[48]);
        int n0 = (blockIdx.x - HEADBLK - 8) * 64 + w * 16;
        const unsigned short* a0 = xh_bf + CC + (size_t)l15 * XH + hi * 8;
        const unsigned short* b0 = Wt_gate + (size_t)(n0 + l15) * DD + hi * 8;
        mmD<DD, XH>(nAct, a0, b0, acc);
        int n = n0 + l15;
        float bv = b_gate[n];
#pragma unroll
        for (int mt = 0; mt < 4; ++mt)
#pragma unroll
            for (int r = 0; r < 4; ++r) {
                int m = mt * 16 + hi * 4 + r;
                gsig[(size_t)m * CC + n] = 1.f / (1.f + expf(-(acc[mt][r] + bv)));
            }
    }
}

extern "C" void kernel_launch(void* const* d_in, const int* in_sizes, int n_in,
                              void* d_out, int out_size, void* d_ws, size_t ws_size,
                              hipStream_t stream) {
    const float* enc     = (const float*)d_in[0];
    const int*   text    = (const int*)d_in[1];
    const int*   lens    = (const int*)d_in[2];
    const float* W_init_h = (const float*)d_in[3];
    const float* b_init_h = (const float*)d_in[4];
    const float* W_init_c = (const float*)d_in[5];
    const float* b_init_c = (const float*)d_in[6];
    const float* W_en    = (const float*)d_in[7];
    const float* b_en    = (const float*)d_in[8];
    const float* W_de    = (const float*)d_in[9];
    const float* b_de    = (const float*)d_in[10];
    const float* W_at    = (const float*)d_in[11];
    const float* b_at    = (const float*)d_in[12];
    const float* W_gate  = (const float*)d_in[13];
    const float* b_gate  = (const float*)d_in[14];
    const float* W_ih    = (const float*)d_in[15];
    const float* b_ih    = (const float*)d_in[16];
    const float* W_hh    = (const float*)d_in[17];
    const float* b_hh    = (const float*)d_in[18];
    const float* embed   = (const float*)d_in[19];
    const float* W_head  = (const float*)d_in[20];
    const float* b_head  = (const float*)d_in[21];

    float* outf = (float*)d_out;
    float* out_pred = outf;                               // B*T*V
    float* out_text = outf + (size_t)BB * TT * VV;        // B*L
    float* out_tlen = out_text + BB * LL;                 // B
    float* out_attn = out_tlen + BB;                      // B*T*P
    float* out_idx  = out_attn + (size_t)BB * TT * PP;    // B

    // ---- workspace layout ----
    char* wsb = (char*)d_ws;
    int* idx  = (int*)wsb;
    int* inv  = idx + 64;
    int* tlen = inv + 64;
    int* ts   = tlen + 64;              // 64*32
    float* fw = (float*)(wsb + 16384);
    float* c_f32 = fw;  fw += (size_t)BB * DD;
    float* de    = fw;  fw += (size_t)BB * AA;
    float* gsig  = fw;  fw += (size_t)BB * CC;
    float* embW  = fw;  fw += (size_t)TT * BB * 2048;
    unsigned short* us = (unsigned short*)fw;
    unsigned short* mean_bf = us;  us += (size_t)BB * CC;
    unsigned short* xh_bf   = us;  us += (size_t)BB * XH;
    unsigned short* hn_bf   = us;  us += (size_t)BB * DD;
    unsigned short* emb_all = us;  us += (size_t)TT * BB * EE;
    unsigned short* en_bf   = us;  us += (size_t)BB * PP * AA;
    unsigned short* enc_bf  = us;  us += (size_t)BB * PP * CC;
    unsigned short* Wt_en   = us;  us += (size_t)AA * CC;
    unsigned short* Wt_de   = us;  us += (size_t)AA * DD;
    unsigned short* Wt_gate = us;  us += (size_t)CC * DD;
    unsigned short* Wt_emb  = us;  us += (size_t)2048 * EE;
    unsigned short* Wt_ihh  = us;  us += (size_t)2048 * XH;
    unsigned short* Wt_ih0  = us;  us += (size_t)DD * CC;
    unsigned short* Wt_ic0  = us;  us += (size_t)DD * CC;
    unsigned short* Wt_head = us;  us += (size_t)VPAD * DD;

    // ---- setup ----
    k_sort<<<1, 64, 0, stream>>>(text, lens, idx, inv, tlen, ts, out_text, out_tlen, out_idx);
    k_cvtenc<<<BB * PP, 256, 0, stream>>>(enc, idx, enc_bf);
    k_meanbf<<<dim3(BB, CC / 256), 256, 0, stream>>>(enc_bf, inv, mean_bf);

    dim3 tb(32, 8);
    k_transcvt<<<dim3(AA / 32, CC / 32), tb, 0, stream>>>(W_en, CC, AA, Wt_en, CC, AA);
    k_transcvt<<<dim3(AA / 32, DD / 32), tb, 0, stream>>>(W_de, DD, AA, Wt_de, DD, AA);
    k_transcvt<<<dim3(CC / 32, DD / 32), tb, 0, stream>>>(W_gate, DD, CC, Wt_gate, DD, CC);
    k_transcvt<<<dim3(CC / 32, CC / 32), tb, 0, stream>>>(W_ih, CC, 2048, Wt_ihh, XH, 2048);
    k_transcvt<<<dim3(CC / 32, DD / 32), tb, 0, stream>>>(W_hh, DD, 2048, Wt_ihh + CC, XH, 2048);
    k_transcvt<<<dim3(CC / 32, DD / 32), tb, 0, stream>>>(W_ih + (size_t)CC * 2048, DD, 2048, Wt_emb, EE, 2048);
    k_transcvt<<<dim3(DD / 32, CC / 32), tb, 0, stream>>>(W_init_h, CC, DD, Wt_ih0, CC, DD);
    k_transcvt<<<dim3(DD / 32, CC / 32), tb, 0, stream>>>(W_init_c, CC, DD, Wt_ic0, CC, DD);
    k_transcvt<<<dim3(VPAD / 32, DD / 32), tb, 0, stream>>>(W_head, DD, VV, Wt_head, DD, VPAD);

    k_init_mfma<<<64, 64, 0, stream>>>(mean_bf, Wt_ih0, Wt_ic0, b_init_h, b_init_c, xh_bf, c_f32);
    k_emball<<<TT * BB, 256, 0, stream>>>(embed, ts, emb_all);
    k_embw<<<dim3(TT, 2048 / 64), 256, 0, stream>>>(emb_all, Wt_emb, b_ih, b_hh, embW);
    k_enattn_mfma<<<PP, 256, 0, stream>>>(enc_bf, Wt_en, b_en, en_bf);
    k_pre0<<<40, 256, 0, stream>>>(xh_bf, Wt_de, b_de, Wt_gate, b_gate, de, gsig);

    // ---- decode loop: 3 launches/step ----
    for (int t = 0; t < TT; ++t) {
        k_actxg<<<dim3(BB, 8), 256, 0, stream>>>(en_bf, de, W_at, b_at, tlen, t, enc_bf, gsig, xh_bf, out_attn);
        k_gateslstm<<<DD / 16, 512, 0, stream>>>(xh_bf, Wt_ihh, embW, tlen, t, xh_bf, c_f32, hn_bf);
        k_head_de_gate<<<HEADBLK + 40, 256, 0, stream>>>(hn_bf, Wt_head, b_head, xh_bf, Wt_de, b_de,
                                                         Wt_gate, b_gate, tlen, t, out_pred, de, gsig);
    }
}